// Round 13
// baseline (1231.395 us; speedup 1.0000x reference)
//
#include <hip/hip_runtime.h>

#define NB 32
#define NP 1024
#define KNB 20
#define INFF __builtin_inff()

// ---------------------------------------------------------------------------
// wave64 cross-lane helpers (shfl-based, proven on this harness r2/r10)
// ---------------------------------------------------------------------------
__device__ __forceinline__ unsigned wred_and(unsigned v) {
#pragma unroll
    for (int off = 32; off >= 1; off >>= 1) v &= (unsigned)__shfl_xor((int)v, off);
    return v;
}
__device__ __forceinline__ unsigned wred_or(unsigned v) {
#pragma unroll
    for (int off = 32; off >= 1; off >>= 1) v |= (unsigned)__shfl_xor((int)v, off);
    return v;
}
__device__ __forceinline__ unsigned wprefix_incl(unsigned v, int lane) {
#pragma unroll
    for (int off = 1; off < 64; off <<= 1) {
        unsigned t = (unsigned)__shfl_up((int)v, off);
        if (lane >= off) v += t;
    }
    return v;
}

// ---------------------------------------------------------------------------
// transpose X [NB*NP, C] -> Xt [NB][C][NP] and squared norms sq [NB*NP]
// ---------------------------------------------------------------------------
template<int C>
__global__ __launch_bounds__(256) void transpose_sq_kernel(const float* __restrict__ X,
                                                           float* __restrict__ Xt,
                                                           float* __restrict__ sq) {
    int p = blockIdx.x * 256 + threadIdx.x;
    int g = p >> 10;
    int lp = p & 1023;
    const float* xr = X + (size_t)p * C;
    float s = 0.f;
#pragma unroll
    for (int c = 0; c < C; c++) {
        float v = xr[c];
        s = fmaf(v, v, s);
        Xt[((size_t)g * C + c) * NP + lp] = v;
    }
    sq[p] = s;
}

// ---------------------------------------------------------------------------
// KNN with one-pass LDS-histogram radix select (replaces r10 bisection).
// One wave = 4 rows. Lane owns j = t*256 + lane*4 + e. Distances bit-identical
// to r2/r10 (both passed absmax=0.0).
// Per row:
//   window: AND/OR of keys -> varying bits [bs:0]; s=max(bs-7,0); 256 bins.
//   histogram: 16 ds_add per lane (self adds 0; self bin = max bin, safe).
//   scan: per-lane 4-bin totals, wave prefix -> locate bin B with rank 19
//         (0-based) and cbelow = #keys in bins < B  (cbelow <= 19).
//   emit bins<B: per-lane popc + wave prefix -> compacted positions.
//   extract need=20-cbelow smallest from bin B by (key,j) lex argmin
//         (matches jax.lax.top_k stable tie rule). Self never wins: its key
//         is UINT_MAX and bin-B real count >= need by construction.
// ---------------------------------------------------------------------------
template<int C>
__global__ __launch_bounds__(256) void knn_kernel(const float* __restrict__ Xt,
                                                  const float* __restrict__ sq,
                                                  int* __restrict__ idx) {
    const int lane = threadIdx.x & 63;
    const int wave = threadIdx.x >> 6;
    const int row0 = blockIdx.x * 16 + wave * 4;
    const int g  = row0 >> 10;
    const int i0 = row0 & 1023;
    const float* __restrict__ Xg  = Xt + (size_t)g * C * NP;
    const float* __restrict__ sqg = sq + g * NP;
    const int j4 = lane * 4;

    __shared__ unsigned hist[4][4][256];   // [wave][row][bin], 16 KB

    // ---- phase 1: dot products (shared j-loads across 4 rows) ----
    float d[4][16];
#pragma unroll
    for (int r = 0; r < 4; r++)
#pragma unroll
        for (int q = 0; q < 16; q++) d[r][q] = 0.f;

#pragma unroll 4
    for (int c = 0; c < C; c++) {
        const float4* col = (const float4*)(Xg + (size_t)c * NP);
        float4 xj[4];
#pragma unroll
        for (int t = 0; t < 4; t++) xj[t] = col[t * 64 + lane];
#pragma unroll
        for (int r = 0; r < 4; r++) {
            float xic = Xg[(size_t)c * NP + i0 + r];
#pragma unroll
            for (int t = 0; t < 4; t++) {
                d[r][t*4+0] = fmaf(xj[t].x, xic, d[r][t*4+0]);
                d[r][t*4+1] = fmaf(xj[t].y, xic, d[r][t*4+1]);
                d[r][t*4+2] = fmaf(xj[t].z, xic, d[r][t*4+2]);
                d[r][t*4+3] = fmaf(xj[t].w, xic, d[r][t*4+3]);
            }
        }
    }

    // ---- phase 2: monotone u32 keys + per-row window (bit-identical dist) ----
    float4 s4[4];
#pragma unroll
    for (int t = 0; t < 4; t++) s4[t] = ((const float4*)sqg)[t * 64 + lane];

    unsigned K[4][16];
    unsigned wmaskA[4]; int sA[4];
#pragma unroll
    for (int r = 0; r < 4; r++) {
        float sqi = sqg[i0 + r];
        unsigned av = 0xFFFFFFFFu, ov = 0u;
#pragma unroll
        for (int t = 0; t < 4; t++) {
#pragma unroll
            for (int e = 0; e < 4; e++) {
                int j = t * 256 + j4 + e;
                float sj = (e == 0) ? s4[t].x : (e == 1) ? s4[t].y : (e == 2) ? s4[t].z : s4[t].w;
                float dist = sqi + sj - 2.f * d[r][t*4+e];
                unsigned u = __float_as_uint(dist);
                unsigned key = u ^ (((int)u < 0) ? 0xFFFFFFFFu : 0x80000000u);
                bool self = (j == i0 + r);
                K[r][t*4+e] = self ? 0xFFFFFFFFu : key;
                av &= self ? 0xFFFFFFFFu : key;
                ov |= self ? 0u : key;
            }
        }
        av = wred_and(av);
        ov = wred_or(ov);
        unsigned x = av ^ ov;
        int b = 31 - __clz((int)x);               // -1 if all keys equal
        wmaskA[r] = (b >= 31) ? 0xFFFFFFFFu : ((b < 0) ? 0u : ((2u << b) - 1u));
        sA[r] = (b >= 7) ? (b - 7) : 0;
    }

    // ---- phases 3-5 per row: histogram -> scan -> emit+extract ----
    const int gbase = g * NP;
#pragma unroll
    for (int r = 0; r < 4; r++) {
        const unsigned wmask = wmaskA[r];
        const int s = sA[r];
        const int selfj = i0 + r;
        unsigned* hrow = &hist[wave][r][0];

        // zero 256 bins (4 per lane, vector store)
        *(uint4*)&hrow[lane * 4] = make_uint4(0u, 0u, 0u, 0u);
        // LDS ops of a wave execute in order; belt-and-braces wait:
        asm volatile("s_waitcnt lgkmcnt(0)" ::: "memory");

        // histogram (self contributes 0; its bin = max bin, index valid)
#pragma unroll
        for (int t = 0; t < 4; t++) {
#pragma unroll
            for (int e = 0; e < 4; e++) {
                int j = t * 256 + j4 + e;
                unsigned bin = (K[r][t*4+e] & wmask) >> s;
                atomicAdd(&hrow[bin], (j != selfj) ? 1u : 0u);
            }
        }
        asm volatile("s_waitcnt lgkmcnt(0)" ::: "memory");

        // scan: lane owns bins [4*lane .. 4*lane+3]
        uint4 h = *(const uint4*)&hrow[lane * 4];
        unsigned T = h.x + h.y + h.z + h.w;
        unsigned P = wprefix_incl(T, lane);       // inclusive prefix
        unsigned E = P - T;                       // exclusive prefix
        bool hit = (E <= 19u) && (19u < P);       // exactly one lane true
        unsigned long long bb = __ballot(hit);
        int lstar = __builtin_ctzll(bb);
        unsigned c1 = E + h.x, c2 = c1 + h.y, c3 = c2 + h.z;
        int Bl; unsigned cbl;
        if (19u < c1)      { Bl = lane * 4 + 0; cbl = E;  }
        else if (19u < c2) { Bl = lane * 4 + 1; cbl = c1; }
        else if (19u < c3) { Bl = lane * 4 + 2; cbl = c2; }
        else               { Bl = lane * 4 + 3; cbl = c3; }
        const unsigned B      = (unsigned)__shfl(Bl, lstar);
        const unsigned cbelow = (unsigned)__shfl((int)cbl, lstar);

        // classify: wm = bins<B (winners), m = bins==B (boundary candidates)
        unsigned wm = 0u, m = 0u;
#pragma unroll
        for (int q = 0; q < 16; q++) {
            unsigned bin = (K[r][q] & wmask) >> s;
            wm |= (bin < B)  ? (1u << q) : 0u;
            m  |= (bin == B) ? (1u << q) : 0u;
        }

        // emit winners, compacted by per-lane popc + wave prefix
        int* outr = idx + (size_t)(row0 + r) * KNB;
        unsigned cnt  = (unsigned)__popc(wm);
        unsigned incl = wprefix_incl(cnt, lane);
        unsigned pos  = incl - cnt;
#pragma unroll
        for (int t = 0; t < 4; t++) {
#pragma unroll
            for (int e = 0; e < 4; e++) {
                int q = t * 4 + e;
                if ((wm >> q) & 1u) { outr[pos] = gbase + t * 256 + j4 + e; pos++; }
            }
        }

        // extract need smallest from bin B, (key, j) lexicographic
        const int need = KNB - (int)cbelow;       // in [1, 20], wave-uniform
        for (int n = 0; n < need; n++) {
            unsigned bk = 0xFFFFFFFFu; int bj = 0x7FFFFFFF;
#pragma unroll
            for (int t = 0; t < 4; t++) {
#pragma unroll
                for (int e = 0; e < 4; e++) {
                    int q = t * 4 + e;
                    if (((m >> q) & 1u) && (K[r][q] < bk)) {   // asc j in lane
                        bk = K[r][q]; bj = t * 256 + j4 + e;
                    }
                }
            }
#pragma unroll
            for (int off = 32; off >= 1; off >>= 1) {
                unsigned ok = (unsigned)__shfl_xor((int)bk, off);
                int      oj = __shfl_xor(bj, off);
                if (ok < bk || (ok == bk && oj < bj)) { bk = ok; bj = oj; }
            }
            if (lane == 0) outr[cbelow + n] = gbase + bj;
            if (((bj >> 2) & 63) == lane)              // owner clears its bit
                m &= ~(1u << (((bj >> 8) << 2) | (bj & 3)));
        }
    }
}

// ---------------------------------------------------------------------------
// Edge-MLP decomposition:  feat@W = xi@(Wt-Wb) + xj@Wb; ReLU & max commute:
//   out_i = relu( A_i + max_j Bm_j ),  A = X@(Wt-Wb)+b,  Bm = X@Wb.
// ---------------------------------------------------------------------------
template<int Cin, int H>
__global__ __launch_bounds__(256) void linear_kernel(const float* __restrict__ X,
                                                     const float* __restrict__ W,
                                                     const float* __restrict__ b,
                                                     float* __restrict__ A,
                                                     float* __restrict__ Bm) {
    int tid = blockIdx.x * 256 + threadIdx.x;
    int i = tid / H;
    int h = tid % H;
    const float* xi = X + (size_t)i * Cin;
    float a = b[h];
    float bm = 0.f;
#pragma unroll 8
    for (int c = 0; c < Cin; c++) {
        float x  = xi[c];
        float wt = W[c * H + h];
        float wb = W[(Cin + c) * H + h];
        a  = fmaf(x, wt - wb, a);
        bm = fmaf(x, wb, bm);
    }
    A[tid]  = a;
    Bm[tid] = bm;
}

// ---------------------------------------------------------------------------
// out_i[h] = relu(A_i[h] + max_{j in knn(i)} Bm_j[h]); float4 over h.
// ---------------------------------------------------------------------------
template<int H>
__global__ __launch_bounds__(256) void gathermax_kernel(const float* __restrict__ A,
                                                        const float* __restrict__ Bm,
                                                        const int* __restrict__ idx,
                                                        float* __restrict__ out) {
    int tid = blockIdx.x * 256 + threadIdx.x;
    int i = tid / (H / 4);
    int q = tid % (H / 4);
    const int* ii = idx + (size_t)i * KNB;
    float4 m = make_float4(-INFF, -INFF, -INFF, -INFF);
#pragma unroll
    for (int r = 0; r < KNB; r++) {
        int j = ii[r];
        float4 v = ((const float4*)(Bm + (size_t)j * H))[q];
        m.x = fmaxf(m.x, v.x); m.y = fmaxf(m.y, v.y);
        m.z = fmaxf(m.z, v.z); m.w = fmaxf(m.w, v.w);
    }
    float4 a = ((const float4*)A)[tid];
    float4 o;
    o.x = fmaxf(a.x + m.x, 0.f); o.y = fmaxf(a.y + m.y, 0.f);
    o.z = fmaxf(a.z + m.z, 0.f); o.w = fmaxf(a.w + m.w, 0.f);
    ((float4*)out)[tid] = o;
}

// ---------------------------------------------------------------------------
// global max-pool over P then FC(128->128) + relu. One block per graph.
// ---------------------------------------------------------------------------
__global__ __launch_bounds__(128) void pool_fc_kernel(const float* __restrict__ h3,
                                                      const float* __restrict__ Wfc,
                                                      const float* __restrict__ bfc,
                                                      float* __restrict__ out) {
    int g = blockIdx.x;
    int c = threadIdx.x;
    const float* hg = h3 + (size_t)g * NP * 128;
    float m = -INFF;
#pragma unroll 8
    for (int p = 0; p < NP; p++)
        m = fmaxf(m, hg[p * 128 + c]);
    __shared__ float pooled[128];
    pooled[c] = m;
    __syncthreads();
    float acc = bfc[c];
#pragma unroll 8
    for (int k = 0; k < 128; k++)
        acc = fmaf(pooled[k], Wfc[k * 128 + c], acc);
    out[g * 128 + c] = fmaxf(acc, 0.f);
}

// ---------------------------------------------------------------------------
// Workspace layout identical to round 10 (~50.6 MB).
// ---------------------------------------------------------------------------
extern "C" void kernel_launch(void* const* d_in, const int* in_sizes, int n_in,
                              void* d_out, int out_size, void* d_ws, size_t ws_size,
                              hipStream_t stream) {
    const float* x   = (const float*)d_in[0];
    const float* W1  = (const float*)d_in[2];
    const float* b1  = (const float*)d_in[3];
    const float* W2  = (const float*)d_in[4];
    const float* b2  = (const float*)d_in[5];
    const float* W3  = (const float*)d_in[6];
    const float* b3  = (const float*)d_in[7];
    const float* Wfc = (const float*)d_in[8];
    const float* bfc = (const float*)d_in[9];
    float* out = (float*)d_out;

    char* ws = (char*)d_ws;
    float* sqb  = (float*)(ws);
    int*   idxb = (int*)  (ws + 131072);
    float* P1   = (float*)(ws + 2752512);
    float* P2   = (float*)(ws + 19529728);
    float* BB   = (float*)(ws + 36306944);
    float* Xt   = BB;   // alias: Xt fully consumed by knn before Bm is written

    const int rowsBlocks = NB * NP / 256;            // 128
    const int knnBlocks  = NB * NP / 16;             // 2048
    const int lin64      = NB * NP * 64 / 256;       // 8192
    const int lin128     = NB * NP * 128 / 256;      // 16384
    const int gm64       = NB * NP * (64/4) / 256;   // 2048
    const int gm128      = NB * NP * (128/4) / 256;  // 4096

    // ---- layer 1 (C=3 -> H=64) ----
    transpose_sq_kernel<3><<<rowsBlocks, 256, 0, stream>>>(x, Xt, sqb);
    knn_kernel<3><<<knnBlocks, 256, 0, stream>>>(Xt, sqb, idxb);
    linear_kernel<3, 64><<<lin64, 256, 0, stream>>>(x, W1, b1, P1, BB);
    gathermax_kernel<64><<<gm64, 256, 0, stream>>>(P1, BB, idxb, P1);

    // ---- layer 2 (C=64 -> H=64) ----
    transpose_sq_kernel<64><<<rowsBlocks, 256, 0, stream>>>(P1, Xt, sqb);
    knn_kernel<64><<<knnBlocks, 256, 0, stream>>>(Xt, sqb, idxb);
    linear_kernel<64, 64><<<lin64, 256, 0, stream>>>(P1, W2, b2, P2, BB);
    gathermax_kernel<64><<<gm64, 256, 0, stream>>>(P2, BB, idxb, P2);

    // ---- layer 3 (C=64 -> H=128) ----
    transpose_sq_kernel<64><<<rowsBlocks, 256, 0, stream>>>(P2, Xt, sqb);
    knn_kernel<64><<<knnBlocks, 256, 0, stream>>>(Xt, sqb, idxb);
    linear_kernel<64, 128><<<lin128, 256, 0, stream>>>(P2, W3, b3, P1, BB);
    gathermax_kernel<128><<<gm128, 256, 0, stream>>>(P1, BB, idxb, P1);

    // ---- global max-pool + FC ----
    pool_fc_kernel<<<NB, 128, 0, stream>>>(P1, Wfc, bfc, out);
}

// Round 15
// 767.361 us; speedup vs baseline: 1.6047x; 1.6047x over previous
//
#include <hip/hip_runtime.h>

#define NB 32
#define NP 1024
#define KNB 20
#define INFF __builtin_inff()

// ---------------------------------------------------------------------------
// wave64 butterfly reductions via __shfl_xor — used ONLY for the per-row
// window init (2 calls/row). The per-round counting no longer uses shuffles.
// ---------------------------------------------------------------------------
__device__ __forceinline__ unsigned wred_and(unsigned v) {
#pragma unroll
    for (int off = 32; off >= 1; off >>= 1) v &= (unsigned)__shfl_xor((int)v, off);
    return v;
}
__device__ __forceinline__ unsigned wred_or(unsigned v) {
#pragma unroll
    for (int off = 32; off >= 1; off >>= 1) v |= (unsigned)__shfl_xor((int)v, off);
    return v;
}

// ---------------------------------------------------------------------------
// transpose X [NB*NP, C] -> Xt [NB][C][NP] and squared norms sq [NB*NP]
// ---------------------------------------------------------------------------
template<int C>
__global__ __launch_bounds__(256) void transpose_sq_kernel(const float* __restrict__ X,
                                                           float* __restrict__ Xt,
                                                           float* __restrict__ sq) {
    int p = blockIdx.x * 256 + threadIdx.x;
    int g = p >> 10;
    int lp = p & 1023;
    const float* xr = X + (size_t)p * C;
    float s = 0.f;
#pragma unroll
    for (int c = 0; c < C; c++) {
        float v = xr[c];
        s = fmaf(v, v, s);
        Xt[((size_t)g * C + c) * NP + lp] = v;
    }
    sq[p] = s;
}

// ---------------------------------------------------------------------------
// KNN: binary-search radix select (r10 algorithm, measured 164 us/dispatch)
// with ONE change: per-round counting via ballot+popcount (SALU pipe,
// no dependent shuffle chains) instead of the 6-deep wred_add butterfly.
// r13's LDS histogram REGRESSED (1.3e7 bank conflicts — clustered float
// keys serialize ds_add); reverted.
// One wave = 4 rows. Lane owns j = t*256 + lane*4 + e. Distance arithmetic
// bit-identical to r2/r10 (both passed absmax=0.0).
// ---------------------------------------------------------------------------
template<int C>
__global__ __launch_bounds__(256) void knn_kernel(const float* __restrict__ Xt,
                                                  const float* __restrict__ sq,
                                                  int* __restrict__ idx) {
    const int lane = threadIdx.x & 63;
    const int wave = threadIdx.x >> 6;
    const int row0 = blockIdx.x * 16 + wave * 4;
    const int g  = row0 >> 10;
    const int i0 = row0 & 1023;
    const float* __restrict__ Xg  = Xt + (size_t)g * C * NP;
    const float* __restrict__ sqg = sq + g * NP;
    const int j4 = lane * 4;

    // ---- phase 1: dot products (shared j-loads across 4 rows) ----
    float d[4][16];
#pragma unroll
    for (int r = 0; r < 4; r++)
#pragma unroll
        for (int q = 0; q < 16; q++) d[r][q] = 0.f;

#pragma unroll 4
    for (int c = 0; c < C; c++) {
        const float4* col = (const float4*)(Xg + (size_t)c * NP);
        float4 xj[4];
#pragma unroll
        for (int t = 0; t < 4; t++) xj[t] = col[t * 64 + lane];
#pragma unroll
        for (int r = 0; r < 4; r++) {
            float xic = Xg[(size_t)c * NP + i0 + r];
#pragma unroll
            for (int t = 0; t < 4; t++) {
                d[r][t*4+0] = fmaf(xj[t].x, xic, d[r][t*4+0]);
                d[r][t*4+1] = fmaf(xj[t].y, xic, d[r][t*4+1]);
                d[r][t*4+2] = fmaf(xj[t].z, xic, d[r][t*4+2]);
                d[r][t*4+3] = fmaf(xj[t].w, xic, d[r][t*4+3]);
            }
        }
    }

    // ---- phase 2: distances -> monotone u32 keys; AND/OR window ----
    float4 s4[4];
#pragma unroll
    for (int t = 0; t < 4; t++) s4[t] = ((const float4*)sqg)[t * 64 + lane];

    unsigned K[4][16];
    unsigned Wlo[4]; unsigned Mex[4]; int bs[4];
    int bmax = 0;
#pragma unroll
    for (int r = 0; r < 4; r++) {
        float sqi = sqg[i0 + r];
        unsigned av = 0xFFFFFFFFu, ov = 0u;
#pragma unroll
        for (int t = 0; t < 4; t++) {
#pragma unroll
            for (int e = 0; e < 4; e++) {
                int j = t * 256 + j4 + e;
                float sj = (e == 0) ? s4[t].x : (e == 1) ? s4[t].y : (e == 2) ? s4[t].z : s4[t].w;
                float dist = sqi + sj - 2.f * d[r][t*4+e];   // identical to r2/r10
                unsigned u = __float_as_uint(dist);
                unsigned key = u ^ (((int)u < 0) ? 0xFFFFFFFFu : 0x80000000u);
                bool self = (j == i0 + r);
                K[r][t*4+e] = self ? 0xFFFFFFFFu : key;
                av &= self ? 0xFFFFFFFFu : key;   // AND over real keys
                ov |= self ? 0u : key;            // OR  over real keys
            }
        }
        av = wred_and(av);
        ov = wred_or(ov);
        unsigned x = av ^ ov;
        int b = 31 - __clz((int)x);               // -1 if all keys equal
        bs[r] = b;
        unsigned wmask = (b >= 31) ? 0xFFFFFFFFu : ((b < 0) ? 0u : ((2u << b) - 1u));
        Wlo[r] = av & ~wmask;                     // common prefix; no key < Wlo
        Mex[r] = 0;
        if (b > bmax) bmax = b;
    }

    // ---- phase 3: bit bisection; counting via ballot+popcount (SALU) ----
    int doneM = 0;
    for (int b = bmax; b >= 0 && doneM != 0xF; b--) {   // uniform bounds
#pragma unroll
        for (int r = 0; r < 4; r++) {
            if ((doneM & (1 << r)) || b > bs[r]) continue;  // uniform guards
            unsigned M = Wlo[r] + (1u << b);
            unsigned tot = 0;
#pragma unroll
            for (int q = 0; q < 16; q++)
                tot += (unsigned)__popcll(__ballot(K[r][q] < M));  // 16 indep v_cmp -> s_bcnt1
            if (tot == KNB)      { Mex[r] = M; doneM |= (1 << r); }
            else if (tot < KNB)  { Wlo[r] = M; }
        }
    }

    // ---- phase 4: emit (identical to r10) ----
    const int gbase = g * NP;
#pragma unroll
    for (int r = 0; r < 4; r++) {
        int* outr = idx + (size_t)(row0 + r) * KNB;
        const bool tie = !(doneM & (1 << r));
        const unsigned M = tie ? Wlo[r] : Mex[r];   // tie: M = p (20th key value)
        unsigned bpos = 0;
#pragma unroll
        for (int t = 0; t < 4; t++) {
#pragma unroll
            for (int e = 0; e < 4; e++) {
                bool w = K[r][t*4+e] < M;           // strict less: unambiguous
                unsigned long long mm = __ballot(w);
                unsigned pos = bpos + __builtin_amdgcn_mbcnt_hi(
                                   (unsigned)(mm >> 32),
                                   __builtin_amdgcn_mbcnt_lo((unsigned)mm, 0u));
                if (w) outr[pos] = gbase + t * 256 + j4 + e;
                bpos += (unsigned)__popcll(mm);
            }
        }
        if (tie) {
            // need = 20 - bpos equals (== M), take smallest j (top_k tie rule)
            const unsigned p = M;
            const int nneed = KNB - (int)bpos;      // >= 1, wave-uniform
            for (int n = 0; n < nneed; n++) {       // rare path
                int jm = 0x7FFFFFFF;
#pragma unroll
                for (int t = 0; t < 4; t++)
#pragma unroll
                    for (int e = 0; e < 4; e++)
                        if (K[r][t*4+e] == p) jm = min(jm, t * 256 + j4 + e);
#pragma unroll
                for (int off = 32; off >= 1; off >>= 1)
                    jm = min(jm, __shfl_xor(jm, off));
                if (((jm >> 2) & 63) == lane) {     // owner lane stores+clears
                    outr[bpos + n] = gbase + jm;
                    int qq = ((jm >> 8) << 2) | (jm & 3);
#pragma unroll
                    for (int q = 0; q < 16; q++)
                        if (q == qq) K[r][q] = 0xFFFFFFFFu;
                }
            }
        }
    }
}

// ---------------------------------------------------------------------------
// Edge-MLP decomposition:  feat@W = xi@(Wt-Wb) + xj@Wb; ReLU & max commute:
//   out_i = relu( A_i + max_j Bm_j ),  A = X@(Wt-Wb)+b,  Bm = X@Wb.
// ---------------------------------------------------------------------------
template<int Cin, int H>
__global__ __launch_bounds__(256) void linear_kernel(const float* __restrict__ X,
                                                     const float* __restrict__ W,
                                                     const float* __restrict__ b,
                                                     float* __restrict__ A,
                                                     float* __restrict__ Bm) {
    int tid = blockIdx.x * 256 + threadIdx.x;
    int i = tid / H;
    int h = tid % H;
    const float* xi = X + (size_t)i * Cin;
    float a = b[h];
    float bm = 0.f;
#pragma unroll 8
    for (int c = 0; c < Cin; c++) {
        float x  = xi[c];
        float wt = W[c * H + h];
        float wb = W[(Cin + c) * H + h];
        a  = fmaf(x, wt - wb, a);
        bm = fmaf(x, wb, bm);
    }
    A[tid]  = a;
    Bm[tid] = bm;
}

// ---------------------------------------------------------------------------
// out_i[h] = relu(A_i[h] + max_{j in knn(i)} Bm_j[h]); float4 over h.
// ---------------------------------------------------------------------------
template<int H>
__global__ __launch_bounds__(256) void gathermax_kernel(const float* __restrict__ A,
                                                        const float* __restrict__ Bm,
                                                        const int* __restrict__ idx,
                                                        float* __restrict__ out) {
    int tid = blockIdx.x * 256 + threadIdx.x;
    int i = tid / (H / 4);
    int q = tid % (H / 4);
    const int* ii = idx + (size_t)i * KNB;
    float4 m = make_float4(-INFF, -INFF, -INFF, -INFF);
#pragma unroll
    for (int r = 0; r < KNB; r++) {
        int j = ii[r];
        float4 v = ((const float4*)(Bm + (size_t)j * H))[q];
        m.x = fmaxf(m.x, v.x); m.y = fmaxf(m.y, v.y);
        m.z = fmaxf(m.z, v.z); m.w = fmaxf(m.w, v.w);
    }
    float4 a = ((const float4*)A)[tid];
    float4 o;
    o.x = fmaxf(a.x + m.x, 0.f); o.y = fmaxf(a.y + m.y, 0.f);
    o.z = fmaxf(a.z + m.z, 0.f); o.w = fmaxf(a.w + m.w, 0.f);
    ((float4*)out)[tid] = o;
}

// ---------------------------------------------------------------------------
// global max-pool over P then FC(128->128) + relu. One block per graph.
// ---------------------------------------------------------------------------
__global__ __launch_bounds__(128) void pool_fc_kernel(const float* __restrict__ h3,
                                                      const float* __restrict__ Wfc,
                                                      const float* __restrict__ bfc,
                                                      float* __restrict__ out) {
    int g = blockIdx.x;
    int c = threadIdx.x;
    const float* hg = h3 + (size_t)g * NP * 128;
    float m = -INFF;
#pragma unroll 8
    for (int p = 0; p < NP; p++)
        m = fmaxf(m, hg[p * 128 + c]);
    __shared__ float pooled[128];
    pooled[c] = m;
    __syncthreads();
    float acc = bfc[c];
#pragma unroll 8
    for (int k = 0; k < 128; k++)
        acc = fmaf(pooled[k], Wfc[k * 128 + c], acc);
    out[g * 128 + c] = fmaxf(acc, 0.f);
}

// ---------------------------------------------------------------------------
// Workspace layout identical to round 10 (~50.6 MB).
// ---------------------------------------------------------------------------
extern "C" void kernel_launch(void* const* d_in, const int* in_sizes, int n_in,
                              void* d_out, int out_size, void* d_ws, size_t ws_size,
                              hipStream_t stream) {
    const float* x   = (const float*)d_in[0];
    const float* W1  = (const float*)d_in[2];
    const float* b1  = (const float*)d_in[3];
    const float* W2  = (const float*)d_in[4];
    const float* b2  = (const float*)d_in[5];
    const float* W3  = (const float*)d_in[6];
    const float* b3  = (const float*)d_in[7];
    const float* Wfc = (const float*)d_in[8];
    const float* bfc = (const float*)d_in[9];
    float* out = (float*)d_out;

    char* ws = (char*)d_ws;
    float* sqb  = (float*)(ws);
    int*   idxb = (int*)  (ws + 131072);
    float* P1   = (float*)(ws + 2752512);
    float* P2   = (float*)(ws + 19529728);
    float* BB   = (float*)(ws + 36306944);
    float* Xt   = BB;   // alias: Xt fully consumed by knn before Bm is written

    const int rowsBlocks = NB * NP / 256;            // 128
    const int knnBlocks  = NB * NP / 16;             // 2048
    const int lin64      = NB * NP * 64 / 256;       // 8192
    const int lin128     = NB * NP * 128 / 256;      // 16384
    const int gm64       = NB * NP * (64/4) / 256;   // 2048
    const int gm128      = NB * NP * (128/4) / 256;  // 4096

    // ---- layer 1 (C=3 -> H=64) ----
    transpose_sq_kernel<3><<<rowsBlocks, 256, 0, stream>>>(x, Xt, sqb);
    knn_kernel<3><<<knnBlocks, 256, 0, stream>>>(Xt, sqb, idxb);
    linear_kernel<3, 64><<<lin64, 256, 0, stream>>>(x, W1, b1, P1, BB);
    gathermax_kernel<64><<<gm64, 256, 0, stream>>>(P1, BB, idxb, P1);

    // ---- layer 2 (C=64 -> H=64) ----
    transpose_sq_kernel<64><<<rowsBlocks, 256, 0, stream>>>(P1, Xt, sqb);
    knn_kernel<64><<<knnBlocks, 256, 0, stream>>>(Xt, sqb, idxb);
    linear_kernel<64, 64><<<lin64, 256, 0, stream>>>(P1, W2, b2, P2, BB);
    gathermax_kernel<64><<<gm64, 256, 0, stream>>>(P2, BB, idxb, P2);

    // ---- layer 3 (C=64 -> H=128) ----
    transpose_sq_kernel<64><<<rowsBlocks, 256, 0, stream>>>(P2, Xt, sqb);
    knn_kernel<64><<<knnBlocks, 256, 0, stream>>>(Xt, sqb, idxb);
    linear_kernel<64, 128><<<lin128, 256, 0, stream>>>(P2, W3, b3, P1, BB);
    gathermax_kernel<128><<<gm128, 256, 0, stream>>>(P1, BB, idxb, P1);

    // ---- global max-pool + FC ----
    pool_fc_kernel<<<NB, 128, 0, stream>>>(P1, Wfc, bfc, out);
}

// Round 16
// 615.447 us; speedup vs baseline: 2.0008x; 1.2468x over previous
//
#include <hip/hip_runtime.h>

#define NB 32
#define NP 1024
#define KNB 20
#define INFF __builtin_inff()

// ---------------------------------------------------------------------------
// wave64 butterfly reductions via __shfl_xor — used ONLY for the per-row
// window init (2 calls/row).
// ---------------------------------------------------------------------------
__device__ __forceinline__ unsigned wred_and(unsigned v) {
#pragma unroll
    for (int off = 32; off >= 1; off >>= 1) v &= (unsigned)__shfl_xor((int)v, off);
    return v;
}
__device__ __forceinline__ unsigned wred_or(unsigned v) {
#pragma unroll
    for (int off = 32; off >= 1; off >>= 1) v |= (unsigned)__shfl_xor((int)v, off);
    return v;
}

// ---------------------------------------------------------------------------
// transpose X [NB*NP, C] -> Xt [NB][C][NP] and squared norms sq [NB*NP]
// ---------------------------------------------------------------------------
template<int C>
__global__ __launch_bounds__(256) void transpose_sq_kernel(const float* __restrict__ X,
                                                           float* __restrict__ Xt,
                                                           float* __restrict__ sq) {
    int p = blockIdx.x * 256 + threadIdx.x;
    int g = p >> 10;
    int lp = p & 1023;
    const float* xr = X + (size_t)p * C;
    float s = 0.f;
#pragma unroll
    for (int c = 0; c < C; c++) {
        float v = xr[c];
        s = fmaf(v, v, s);
        Xt[((size_t)g * C + c) * NP + lp] = v;
    }
    sq[p] = s;
}

// ---------------------------------------------------------------------------
// KNN: binary-search radix select, counting via ballot+popcount (r15 source,
// measured: total 767 us, knn < 159 us, absmax 0.0). Unchanged this round.
// ---------------------------------------------------------------------------
template<int C>
__global__ __launch_bounds__(256) void knn_kernel(const float* __restrict__ Xt,
                                                  const float* __restrict__ sq,
                                                  int* __restrict__ idx) {
    const int lane = threadIdx.x & 63;
    const int wave = threadIdx.x >> 6;
    const int row0 = blockIdx.x * 16 + wave * 4;
    const int g  = row0 >> 10;
    const int i0 = row0 & 1023;
    const float* __restrict__ Xg  = Xt + (size_t)g * C * NP;
    const float* __restrict__ sqg = sq + g * NP;
    const int j4 = lane * 4;

    // ---- phase 1: dot products (shared j-loads across 4 rows) ----
    float d[4][16];
#pragma unroll
    for (int r = 0; r < 4; r++)
#pragma unroll
        for (int q = 0; q < 16; q++) d[r][q] = 0.f;

#pragma unroll 4
    for (int c = 0; c < C; c++) {
        const float4* col = (const float4*)(Xg + (size_t)c * NP);
        float4 xj[4];
#pragma unroll
        for (int t = 0; t < 4; t++) xj[t] = col[t * 64 + lane];
#pragma unroll
        for (int r = 0; r < 4; r++) {
            float xic = Xg[(size_t)c * NP + i0 + r];
#pragma unroll
            for (int t = 0; t < 4; t++) {
                d[r][t*4+0] = fmaf(xj[t].x, xic, d[r][t*4+0]);
                d[r][t*4+1] = fmaf(xj[t].y, xic, d[r][t*4+1]);
                d[r][t*4+2] = fmaf(xj[t].z, xic, d[r][t*4+2]);
                d[r][t*4+3] = fmaf(xj[t].w, xic, d[r][t*4+3]);
            }
        }
    }

    // ---- phase 2: distances -> monotone u32 keys; AND/OR window ----
    float4 s4[4];
#pragma unroll
    for (int t = 0; t < 4; t++) s4[t] = ((const float4*)sqg)[t * 64 + lane];

    unsigned K[4][16];
    unsigned Wlo[4]; unsigned Mex[4]; int bs[4];
    int bmax = 0;
#pragma unroll
    for (int r = 0; r < 4; r++) {
        float sqi = sqg[i0 + r];
        unsigned av = 0xFFFFFFFFu, ov = 0u;
#pragma unroll
        for (int t = 0; t < 4; t++) {
#pragma unroll
            for (int e = 0; e < 4; e++) {
                int j = t * 256 + j4 + e;
                float sj = (e == 0) ? s4[t].x : (e == 1) ? s4[t].y : (e == 2) ? s4[t].z : s4[t].w;
                float dist = sqi + sj - 2.f * d[r][t*4+e];   // identical to r2/r10
                unsigned u = __float_as_uint(dist);
                unsigned key = u ^ (((int)u < 0) ? 0xFFFFFFFFu : 0x80000000u);
                bool self = (j == i0 + r);
                K[r][t*4+e] = self ? 0xFFFFFFFFu : key;
                av &= self ? 0xFFFFFFFFu : key;
                ov |= self ? 0u : key;
            }
        }
        av = wred_and(av);
        ov = wred_or(ov);
        unsigned x = av ^ ov;
        int b = 31 - __clz((int)x);               // -1 if all keys equal
        bs[r] = b;
        unsigned wmask = (b >= 31) ? 0xFFFFFFFFu : ((b < 0) ? 0u : ((2u << b) - 1u));
        Wlo[r] = av & ~wmask;                     // common prefix; no key < Wlo
        Mex[r] = 0;
        if (b > bmax) bmax = b;
    }

    // ---- phase 3: bit bisection; counting via ballot+popcount (SALU) ----
    int doneM = 0;
    for (int b = bmax; b >= 0 && doneM != 0xF; b--) {   // uniform bounds
#pragma unroll
        for (int r = 0; r < 4; r++) {
            if ((doneM & (1 << r)) || b > bs[r]) continue;  // uniform guards
            unsigned M = Wlo[r] + (1u << b);
            unsigned tot = 0;
#pragma unroll
            for (int q = 0; q < 16; q++)
                tot += (unsigned)__popcll(__ballot(K[r][q] < M));  // v_cmp -> s_bcnt1
            if (tot == KNB)      { Mex[r] = M; doneM |= (1 << r); }
            else if (tot < KNB)  { Wlo[r] = M; }
        }
    }

    // ---- phase 4: emit ----
    const int gbase = g * NP;
#pragma unroll
    for (int r = 0; r < 4; r++) {
        int* outr = idx + (size_t)(row0 + r) * KNB;
        const bool tie = !(doneM & (1 << r));
        const unsigned M = tie ? Wlo[r] : Mex[r];   // tie: M = p (20th key value)
        unsigned bpos = 0;
#pragma unroll
        for (int t = 0; t < 4; t++) {
#pragma unroll
            for (int e = 0; e < 4; e++) {
                bool w = K[r][t*4+e] < M;           // strict less: unambiguous
                unsigned long long mm = __ballot(w);
                unsigned pos = bpos + __builtin_amdgcn_mbcnt_hi(
                                   (unsigned)(mm >> 32),
                                   __builtin_amdgcn_mbcnt_lo((unsigned)mm, 0u));
                if (w) outr[pos] = gbase + t * 256 + j4 + e;
                bpos += (unsigned)__popcll(mm);
            }
        }
        if (tie) {
            const unsigned p = M;
            const int nneed = KNB - (int)bpos;      // >= 1, wave-uniform
            for (int n = 0; n < nneed; n++) {       // rare path
                int jm = 0x7FFFFFFF;
#pragma unroll
                for (int t = 0; t < 4; t++)
#pragma unroll
                    for (int e = 0; e < 4; e++)
                        if (K[r][t*4+e] == p) jm = min(jm, t * 256 + j4 + e);
#pragma unroll
                for (int off = 32; off >= 1; off >>= 1)
                    jm = min(jm, __shfl_xor(jm, off));
                if (((jm >> 2) & 63) == lane) {     // owner lane stores+clears
                    outr[bpos + n] = gbase + jm;
                    int qq = ((jm >> 8) << 2) | (jm & 3);
#pragma unroll
                    for (int q = 0; q < 16; q++)
                        if (q == qq) K[r][q] = 0xFFFFFFFFu;
                }
            }
        }
    }
}

// ---------------------------------------------------------------------------
// Edge-MLP decomposition:  feat@W = xi@(Wt-Wb) + xj@Wb; ReLU & max commute:
//   out_i = relu( A_i + max_j Bm_j ),  A = X@(Wt-Wb)+b,  Bm = X@Wb.
// ---------------------------------------------------------------------------
template<int Cin, int H>
__global__ __launch_bounds__(256) void linear_kernel(const float* __restrict__ X,
                                                     const float* __restrict__ W,
                                                     const float* __restrict__ b,
                                                     float* __restrict__ A,
                                                     float* __restrict__ Bm) {
    int tid = blockIdx.x * 256 + threadIdx.x;
    int i = tid / H;
    int h = tid % H;
    const float* xi = X + (size_t)i * Cin;
    float a = b[h];
    float bm = 0.f;
#pragma unroll 8
    for (int c = 0; c < Cin; c++) {
        float x  = xi[c];
        float wt = W[c * H + h];
        float wb = W[(Cin + c) * H + h];
        a  = fmaf(x, wt - wb, a);
        bm = fmaf(x, wb, bm);
    }
    A[tid]  = a;
    Bm[tid] = bm;
}

// ---------------------------------------------------------------------------
// layers 1-2: out_i[h] = relu(A_i[h] + max_knn Bm_j[h]); float4 over h.
// ---------------------------------------------------------------------------
template<int H>
__global__ __launch_bounds__(256) void gathermax_kernel(const float* __restrict__ A,
                                                        const float* __restrict__ Bm,
                                                        const int* __restrict__ idx,
                                                        float* __restrict__ out) {
    int tid = blockIdx.x * 256 + threadIdx.x;
    int i = tid / (H / 4);
    int q = tid % (H / 4);
    const int* ii = idx + (size_t)i * KNB;
    float4 m = make_float4(-INFF, -INFF, -INFF, -INFF);
#pragma unroll
    for (int r = 0; r < KNB; r++) {
        int j = ii[r];
        float4 v = ((const float4*)(Bm + (size_t)j * H))[q];
        m.x = fmaxf(m.x, v.x); m.y = fmaxf(m.y, v.y);
        m.z = fmaxf(m.z, v.z); m.w = fmaxf(m.w, v.w);
    }
    float4 a = ((const float4*)A)[tid];
    float4 o;
    o.x = fmaxf(a.x + m.x, 0.f); o.y = fmaxf(a.y + m.y, 0.f);
    o.z = fmaxf(a.z + m.z, 0.f); o.w = fmaxf(a.w + m.w, 0.f);
    ((float4*)out)[tid] = o;
}

// ---------------------------------------------------------------------------
// layer 3 FUSED with global max-pool: computes o = relu(A+max) like
// gathermax<128> but reduces max per-block in LDS and atomicMax's into
// pooled[g][c] (int-compare valid: o >= 0 post-relu). No h3 materialized.
// Block = 256 threads = 8 consecutive points x 32 float4-groups (same graph:
// 1024 % 8 == 0).
// ---------------------------------------------------------------------------
__global__ __launch_bounds__(256) void gathermax_pool_kernel(const float* __restrict__ A,
                                                             const float* __restrict__ Bm,
                                                             const int* __restrict__ idx,
                                                             int* __restrict__ pooled) {
    int tid = blockIdx.x * 256 + threadIdx.x;
    int i = tid >> 5;            // point index   (H/4 = 32 groups per point)
    int q = tid & 31;            // float4 group
    int g = i >> 10;             // graph (uniform per block)

    __shared__ int smax[128];
    if (threadIdx.x < 128) smax[threadIdx.x] = 0;    // 0 == +0.0f bits
    __syncthreads();

    const int* ii = idx + (size_t)i * KNB;
    float4 m = make_float4(-INFF, -INFF, -INFF, -INFF);
#pragma unroll
    for (int r = 0; r < KNB; r++) {
        int j = ii[r];
        float4 v = ((const float4*)(Bm + (size_t)j * 128))[q];
        m.x = fmaxf(m.x, v.x); m.y = fmaxf(m.y, v.y);
        m.z = fmaxf(m.z, v.z); m.w = fmaxf(m.w, v.w);
    }
    float4 a = ((const float4*)A)[tid];
    float4 o;
    o.x = fmaxf(a.x + m.x, 0.f); o.y = fmaxf(a.y + m.y, 0.f);
    o.z = fmaxf(a.z + m.z, 0.f); o.w = fmaxf(a.w + m.w, 0.f);

    atomicMax(&smax[q*4+0], __float_as_int(o.x));
    atomicMax(&smax[q*4+1], __float_as_int(o.y));
    atomicMax(&smax[q*4+2], __float_as_int(o.z));
    atomicMax(&smax[q*4+3], __float_as_int(o.w));
    __syncthreads();
    if (threadIdx.x < 128)
        atomicMax(&pooled[g * 128 + threadIdx.x], smax[threadIdx.x]);
}

// zero the pooled buffer (4096 ints) — kernel, not memset (graph-capture safe)
__global__ __launch_bounds__(256) void zero_pool_kernel(int* __restrict__ pooled) {
    pooled[blockIdx.x * 256 + threadIdx.x] = 0;
}

// FC(128->128) + relu on the pooled vector. One block per graph.
__global__ __launch_bounds__(128) void fc_kernel(const int* __restrict__ pooled,
                                                 const float* __restrict__ Wfc,
                                                 const float* __restrict__ bfc,
                                                 float* __restrict__ out) {
    int g = blockIdx.x;
    int c = threadIdx.x;
    __shared__ float pl[128];
    pl[c] = __int_as_float(pooled[g * 128 + c]);
    __syncthreads();
    float acc = bfc[c];
#pragma unroll 8
    for (int k = 0; k < 128; k++)
        acc = fmaf(pl[k], Wfc[k * 128 + c], acc);
    out[g * 128 + c] = fmaxf(acc, 0.f);
}

// ---------------------------------------------------------------------------
// Workspace layout (~50.6 MB), as r10/r15. pooled aliases the head of P2
// (dead after linear3's read) — zeroed on-stream right before use.
// ---------------------------------------------------------------------------
extern "C" void kernel_launch(void* const* d_in, const int* in_sizes, int n_in,
                              void* d_out, int out_size, void* d_ws, size_t ws_size,
                              hipStream_t stream) {
    const float* x   = (const float*)d_in[0];
    const float* W1  = (const float*)d_in[2];
    const float* b1  = (const float*)d_in[3];
    const float* W2  = (const float*)d_in[4];
    const float* b2  = (const float*)d_in[5];
    const float* W3  = (const float*)d_in[6];
    const float* b3  = (const float*)d_in[7];
    const float* Wfc = (const float*)d_in[8];
    const float* bfc = (const float*)d_in[9];
    float* out = (float*)d_out;

    char* ws = (char*)d_ws;
    float* sqb  = (float*)(ws);
    int*   idxb = (int*)  (ws + 131072);
    float* P1   = (float*)(ws + 2752512);
    float* P2   = (float*)(ws + 19529728);
    float* BB   = (float*)(ws + 36306944);
    float* Xt   = BB;            // alias: consumed by knn before Bm written
    int* pooled = (int*)P2;      // alias: P2 dead after linear3 reads it

    const int rowsBlocks = NB * NP / 256;            // 128
    const int knnBlocks  = NB * NP / 16;             // 2048
    const int lin64      = NB * NP * 64 / 256;       // 8192
    const int lin128     = NB * NP * 128 / 256;      // 16384
    const int gm64       = NB * NP * (64/4) / 256;   // 2048
    const int gmp128     = NB * NP * 32 / 256;       // 4096

    // ---- layer 1 (C=3 -> H=64) ----
    transpose_sq_kernel<3><<<rowsBlocks, 256, 0, stream>>>(x, Xt, sqb);
    knn_kernel<3><<<knnBlocks, 256, 0, stream>>>(Xt, sqb, idxb);
    linear_kernel<3, 64><<<lin64, 256, 0, stream>>>(x, W1, b1, P1, BB);
    gathermax_kernel<64><<<gm64, 256, 0, stream>>>(P1, BB, idxb, P1);

    // ---- layer 2 (C=64 -> H=64) ----
    transpose_sq_kernel<64><<<rowsBlocks, 256, 0, stream>>>(P1, Xt, sqb);
    knn_kernel<64><<<knnBlocks, 256, 0, stream>>>(Xt, sqb, idxb);
    linear_kernel<64, 64><<<lin64, 256, 0, stream>>>(P1, W2, b2, P2, BB);
    gathermax_kernel<64><<<gm64, 256, 0, stream>>>(P2, BB, idxb, P2);

    // ---- layer 3 (C=64 -> H=128), pool fused ----
    transpose_sq_kernel<64><<<rowsBlocks, 256, 0, stream>>>(P2, Xt, sqb);
    knn_kernel<64><<<knnBlocks, 256, 0, stream>>>(Xt, sqb, idxb);
    linear_kernel<64, 128><<<lin128, 256, 0, stream>>>(P2, W3, b3, P1, BB);
    zero_pool_kernel<<<NB * 128 / 256, 256, 0, stream>>>(pooled);   // P2 now dead
    gathermax_pool_kernel<<<gmp128, 256, 0, stream>>>(P1, BB, idxb, pooled);

    // ---- FC on pooled ----
    fc_kernel<<<NB, 128, 0, stream>>>(pooled, Wfc, bfc, out);
}

// Round 17
// 608.625 us; speedup vs baseline: 2.0232x; 1.0112x over previous
//
#include <hip/hip_runtime.h>

#define NB 32
#define NP 1024
#define KNB 20
#define INFF __builtin_inff()

// ---------------------------------------------------------------------------
// wave64 butterfly reductions via __shfl_xor — window init only (2/row).
// Results are wave-uniform; callers readfirstlane them into SGPRs so the
// compiler emits scalar control flow for the bisection loop.
// ---------------------------------------------------------------------------
__device__ __forceinline__ unsigned wred_and(unsigned v) {
#pragma unroll
    for (int off = 32; off >= 1; off >>= 1) v &= (unsigned)__shfl_xor((int)v, off);
    return v;
}
__device__ __forceinline__ unsigned wred_or(unsigned v) {
#pragma unroll
    for (int off = 32; off >= 1; off >>= 1) v |= (unsigned)__shfl_xor((int)v, off);
    return v;
}

// ---------------------------------------------------------------------------
// transpose X [NB*NP, C] -> Xt [NB][C][NP] and squared norms sq [NB*NP]
// ---------------------------------------------------------------------------
template<int C>
__global__ __launch_bounds__(256) void transpose_sq_kernel(const float* __restrict__ X,
                                                           float* __restrict__ Xt,
                                                           float* __restrict__ sq) {
    int p = blockIdx.x * 256 + threadIdx.x;
    int g = p >> 10;
    int lp = p & 1023;
    const float* xr = X + (size_t)p * C;
    float s = 0.f;
#pragma unroll
    for (int c = 0; c < C; c++) {
        float v = xr[c];
        s = fmaf(v, v, s);
        Xt[((size_t)g * C + c) * NP + lp] = v;
    }
    sq[p] = s;
}

// ---------------------------------------------------------------------------
// KNN: binary-search radix select with ballot+popcount counting (r15) and
// NEW: selection state scalarized via readfirstlane (r16 PMC showed ~15k
// VALU instr/wave — 4x static estimate — from divergent-compiled uniform
// branches; forcing SGPRs moves the bisection control to SALU).
// One wave = 4 rows. Lane owns j = t*256 + lane*4 + e. Distance arithmetic
// bit-identical to r2/r10/r15 (all passed absmax=0.0).
// ---------------------------------------------------------------------------
template<int C>
__global__ __launch_bounds__(256) void knn_kernel(const float* __restrict__ Xt,
                                                  const float* __restrict__ sq,
                                                  int* __restrict__ idx) {
    const int lane = threadIdx.x & 63;
    const int wave = threadIdx.x >> 6;
    const int row0 = blockIdx.x * 16 + wave * 4;
    const int g  = row0 >> 10;
    const int i0 = row0 & 1023;
    const float* __restrict__ Xg  = Xt + (size_t)g * C * NP;
    const float* __restrict__ sqg = sq + g * NP;
    const int j4 = lane * 4;

    // ---- phase 1: dot products (shared j-loads across 4 rows) ----
    float d[4][16];
#pragma unroll
    for (int r = 0; r < 4; r++)
#pragma unroll
        for (int q = 0; q < 16; q++) d[r][q] = 0.f;

#pragma unroll 4
    for (int c = 0; c < C; c++) {
        const float4* col = (const float4*)(Xg + (size_t)c * NP);
        float4 xj[4];
#pragma unroll
        for (int t = 0; t < 4; t++) xj[t] = col[t * 64 + lane];
#pragma unroll
        for (int r = 0; r < 4; r++) {
            float xic = Xg[(size_t)c * NP + i0 + r];
#pragma unroll
            for (int t = 0; t < 4; t++) {
                d[r][t*4+0] = fmaf(xj[t].x, xic, d[r][t*4+0]);
                d[r][t*4+1] = fmaf(xj[t].y, xic, d[r][t*4+1]);
                d[r][t*4+2] = fmaf(xj[t].z, xic, d[r][t*4+2]);
                d[r][t*4+3] = fmaf(xj[t].w, xic, d[r][t*4+3]);
            }
        }
    }

    // ---- phase 2: distances -> monotone u32 keys; AND/OR window (SGPR) ----
    float4 s4[4];
#pragma unroll
    for (int t = 0; t < 4; t++) s4[t] = ((const float4*)sqg)[t * 64 + lane];

    unsigned K[4][16];
    unsigned Wlo[4]; unsigned Mex[4]; int bs[4];
    int bmax = 0;
#pragma unroll
    for (int r = 0; r < 4; r++) {
        float sqi = sqg[i0 + r];
        unsigned av = 0xFFFFFFFFu, ov = 0u;
#pragma unroll
        for (int t = 0; t < 4; t++) {
#pragma unroll
            for (int e = 0; e < 4; e++) {
                int j = t * 256 + j4 + e;
                float sj = (e == 0) ? s4[t].x : (e == 1) ? s4[t].y : (e == 2) ? s4[t].z : s4[t].w;
                float dist = sqi + sj - 2.f * d[r][t*4+e];   // identical to r2/r10
                unsigned u = __float_as_uint(dist);
                unsigned key = u ^ (((int)u < 0) ? 0xFFFFFFFFu : 0x80000000u);
                bool self = (j == i0 + r);
                K[r][t*4+e] = self ? 0xFFFFFFFFu : key;
                av &= self ? 0xFFFFFFFFu : key;
                ov |= self ? 0u : key;
            }
        }
        // butterfly results are uniform; force into SGPRs -> scalar branches
        av = (unsigned)__builtin_amdgcn_readfirstlane((int)wred_and(av));
        ov = (unsigned)__builtin_amdgcn_readfirstlane((int)wred_or(ov));
        unsigned x = av ^ ov;
        int b = 31 - __clz((int)x);               // -1 if all keys equal
        bs[r] = b;
        unsigned wmask = (b >= 31) ? 0xFFFFFFFFu : ((b < 0) ? 0u : ((2u << b) - 1u));
        Wlo[r] = av & ~wmask;                     // common prefix; no key < Wlo
        Mex[r] = 0;
        if (b > bmax) bmax = b;
    }

    // ---- phase 3: bit bisection; count via ballot+popcount; scalar ctrl ----
    int doneM = 0;
    for (int b = bmax; b >= 0 && doneM != 0xF; b--) {   // scalar bounds
#pragma unroll
        for (int r = 0; r < 4; r++) {
            if ((doneM & (1 << r)) || b > bs[r]) continue;  // scalar guards
            unsigned M = Wlo[r] + (1u << b);                // SGPR
            unsigned tot = 0;
#pragma unroll
            for (int q = 0; q < 16; q++)
                tot += (unsigned)__popcll(__ballot(K[r][q] < M));  // v_cmp -> s_bcnt1
            if (tot == KNB)      { Mex[r] = M; doneM |= (1 << r); }
            else if (tot < KNB)  { Wlo[r] = M; }
        }
    }

    // ---- phase 4: emit ----
    const int gbase = g * NP;
#pragma unroll
    for (int r = 0; r < 4; r++) {
        int* outr = idx + (size_t)(row0 + r) * KNB;
        const bool tie = !(doneM & (1 << r));
        const unsigned M = tie ? Wlo[r] : Mex[r];   // tie: M = p (20th key value)
        unsigned bpos = 0;
#pragma unroll
        for (int t = 0; t < 4; t++) {
#pragma unroll
            for (int e = 0; e < 4; e++) {
                bool w = K[r][t*4+e] < M;           // strict less: unambiguous
                unsigned long long mm = __ballot(w);
                unsigned pos = bpos + __builtin_amdgcn_mbcnt_hi(
                                   (unsigned)(mm >> 32),
                                   __builtin_amdgcn_mbcnt_lo((unsigned)mm, 0u));
                if (w) outr[pos] = gbase + t * 256 + j4 + e;
                bpos += (unsigned)__popcll(mm);
            }
        }
        if (tie) {
            const unsigned p = M;
            const int nneed = KNB - (int)bpos;      // >= 1, scalar
            for (int n = 0; n < nneed; n++) {       // rare path
                int jm = 0x7FFFFFFF;
#pragma unroll
                for (int t = 0; t < 4; t++)
#pragma unroll
                    for (int e = 0; e < 4; e++)
                        if (K[r][t*4+e] == p) jm = min(jm, t * 256 + j4 + e);
#pragma unroll
                for (int off = 32; off >= 1; off >>= 1)
                    jm = min(jm, __shfl_xor(jm, off));
                if (((jm >> 2) & 63) == lane) {     // owner lane stores+clears
                    outr[bpos + n] = gbase + jm;
                    int qq = ((jm >> 8) << 2) | (jm & 3);
#pragma unroll
                    for (int q = 0; q < 16; q++)
                        if (q == qq) K[r][q] = 0xFFFFFFFFu;
                }
            }
        }
    }
}

// ---------------------------------------------------------------------------
// Edge-MLP decomposition:  feat@W = xi@(Wt-Wb) + xj@Wb; ReLU & max commute:
//   out_i = relu( A_i + max_j Bm_j ),  A = X@(Wt-Wb)+b,  Bm = X@Wb.
// ---------------------------------------------------------------------------
template<int Cin, int H>
__global__ __launch_bounds__(256) void linear_kernel(const float* __restrict__ X,
                                                     const float* __restrict__ W,
                                                     const float* __restrict__ b,
                                                     float* __restrict__ A,
                                                     float* __restrict__ Bm) {
    int tid = blockIdx.x * 256 + threadIdx.x;
    int i = tid / H;
    int h = tid % H;
    const float* xi = X + (size_t)i * Cin;
    float a = b[h];
    float bm = 0.f;
#pragma unroll 8
    for (int c = 0; c < Cin; c++) {
        float x  = xi[c];
        float wt = W[c * H + h];
        float wb = W[(Cin + c) * H + h];
        a  = fmaf(x, wt - wb, a);
        bm = fmaf(x, wb, bm);
    }
    A[tid]  = a;
    Bm[tid] = bm;
}

// ---------------------------------------------------------------------------
// layers 1-2: out_i[h] = relu(A_i[h] + max_knn Bm_j[h]); float4 over h.
// ---------------------------------------------------------------------------
template<int H>
__global__ __launch_bounds__(256) void gathermax_kernel(const float* __restrict__ A,
                                                        const float* __restrict__ Bm,
                                                        const int* __restrict__ idx,
                                                        float* __restrict__ out) {
    int tid = blockIdx.x * 256 + threadIdx.x;
    int i = tid / (H / 4);
    int q = tid % (H / 4);
    const int* ii = idx + (size_t)i * KNB;
    float4 m = make_float4(-INFF, -INFF, -INFF, -INFF);
#pragma unroll
    for (int r = 0; r < KNB; r++) {
        int j = ii[r];
        float4 v = ((const float4*)(Bm + (size_t)j * H))[q];
        m.x = fmaxf(m.x, v.x); m.y = fmaxf(m.y, v.y);
        m.z = fmaxf(m.z, v.z); m.w = fmaxf(m.w, v.w);
    }
    float4 a = ((const float4*)A)[tid];
    float4 o;
    o.x = fmaxf(a.x + m.x, 0.f); o.y = fmaxf(a.y + m.y, 0.f);
    o.z = fmaxf(a.z + m.z, 0.f); o.w = fmaxf(a.w + m.w, 0.f);
    ((float4*)out)[tid] = o;
}

// ---------------------------------------------------------------------------
// layer 3 FUSED with global max-pool (r16, measured: pool path off top-5).
// ---------------------------------------------------------------------------
__global__ __launch_bounds__(256) void gathermax_pool_kernel(const float* __restrict__ A,
                                                             const float* __restrict__ Bm,
                                                             const int* __restrict__ idx,
                                                             int* __restrict__ pooled) {
    int tid = blockIdx.x * 256 + threadIdx.x;
    int i = tid >> 5;            // point index   (H/4 = 32 groups per point)
    int q = tid & 31;            // float4 group
    int g = i >> 10;             // graph (uniform per block)

    __shared__ int smax[128];
    if (threadIdx.x < 128) smax[threadIdx.x] = 0;    // 0 == +0.0f bits
    __syncthreads();

    const int* ii = idx + (size_t)i * KNB;
    float4 m = make_float4(-INFF, -INFF, -INFF, -INFF);
#pragma unroll
    for (int r = 0; r < KNB; r++) {
        int j = ii[r];
        float4 v = ((const float4*)(Bm + (size_t)j * 128))[q];
        m.x = fmaxf(m.x, v.x); m.y = fmaxf(m.y, v.y);
        m.z = fmaxf(m.z, v.z); m.w = fmaxf(m.w, v.w);
    }
    float4 a = ((const float4*)A)[tid];
    float4 o;
    o.x = fmaxf(a.x + m.x, 0.f); o.y = fmaxf(a.y + m.y, 0.f);
    o.z = fmaxf(a.z + m.z, 0.f); o.w = fmaxf(a.w + m.w, 0.f);

    atomicMax(&smax[q*4+0], __float_as_int(o.x));
    atomicMax(&smax[q*4+1], __float_as_int(o.y));
    atomicMax(&smax[q*4+2], __float_as_int(o.z));
    atomicMax(&smax[q*4+3], __float_as_int(o.w));
    __syncthreads();
    if (threadIdx.x < 128)
        atomicMax(&pooled[g * 128 + threadIdx.x], smax[threadIdx.x]);
}

// zero the pooled buffer (4096 ints) — kernel, not memset (graph-capture safe)
__global__ __launch_bounds__(256) void zero_pool_kernel(int* __restrict__ pooled) {
    pooled[blockIdx.x * 256 + threadIdx.x] = 0;
}

// FC(128->128) + relu on the pooled vector. One block per graph.
__global__ __launch_bounds__(128) void fc_kernel(const int* __restrict__ pooled,
                                                 const float* __restrict__ Wfc,
                                                 const float* __restrict__ bfc,
                                                 float* __restrict__ out) {
    int g = blockIdx.x;
    int c = threadIdx.x;
    __shared__ float pl[128];
    pl[c] = __int_as_float(pooled[g * 128 + c]);
    __syncthreads();
    float acc = bfc[c];
#pragma unroll 8
    for (int k = 0; k < 128; k++)
        acc = fmaf(pl[k], Wfc[k * 128 + c], acc);
    out[g * 128 + c] = fmaxf(acc, 0.f);
}

// ---------------------------------------------------------------------------
// Workspace layout (~50.6 MB), as r16. pooled aliases the head of P2.
// ---------------------------------------------------------------------------
extern "C" void kernel_launch(void* const* d_in, const int* in_sizes, int n_in,
                              void* d_out, int out_size, void* d_ws, size_t ws_size,
                              hipStream_t stream) {
    const float* x   = (const float*)d_in[0];
    const float* W1  = (const float*)d_in[2];
    const float* b1  = (const float*)d_in[3];
    const float* W2  = (const float*)d_in[4];
    const float* b2  = (const float*)d_in[5];
    const float* W3  = (const float*)d_in[6];
    const float* b3  = (const float*)d_in[7];
    const float* Wfc = (const float*)d_in[8];
    const float* bfc = (const float*)d_in[9];
    float* out = (float*)d_out;

    char* ws = (char*)d_ws;
    float* sqb  = (float*)(ws);
    int*   idxb = (int*)  (ws + 131072);
    float* P1   = (float*)(ws + 2752512);
    float* P2   = (float*)(ws + 19529728);
    float* BB   = (float*)(ws + 36306944);
    float* Xt   = BB;            // alias: consumed by knn before Bm written
    int* pooled = (int*)P2;      // alias: P2 dead after linear3 reads it

    const int rowsBlocks = NB * NP / 256;            // 128
    const int knnBlocks  = NB * NP / 16;             // 2048
    const int lin64      = NB * NP * 64 / 256;       // 8192
    const int lin128     = NB * NP * 128 / 256;      // 16384
    const int gm64       = NB * NP * (64/4) / 256;   // 2048
    const int gmp128     = NB * NP * 32 / 256;       // 4096

    // ---- layer 1 (C=3 -> H=64) ----
    transpose_sq_kernel<3><<<rowsBlocks, 256, 0, stream>>>(x, Xt, sqb);
    knn_kernel<3><<<knnBlocks, 256, 0, stream>>>(Xt, sqb, idxb);
    linear_kernel<3, 64><<<lin64, 256, 0, stream>>>(x, W1, b1, P1, BB);
    gathermax_kernel<64><<<gm64, 256, 0, stream>>>(P1, BB, idxb, P1);

    // ---- layer 2 (C=64 -> H=64) ----
    transpose_sq_kernel<64><<<rowsBlocks, 256, 0, stream>>>(P1, Xt, sqb);
    knn_kernel<64><<<knnBlocks, 256, 0, stream>>>(Xt, sqb, idxb);
    linear_kernel<64, 64><<<lin64, 256, 0, stream>>>(P1, W2, b2, P2, BB);
    gathermax_kernel<64><<<gm64, 256, 0, stream>>>(P2, BB, idxb, P2);

    // ---- layer 3 (C=64 -> H=128), pool fused ----
    transpose_sq_kernel<64><<<rowsBlocks, 256, 0, stream>>>(P2, Xt, sqb);
    knn_kernel<64><<<knnBlocks, 256, 0, stream>>>(Xt, sqb, idxb);
    linear_kernel<64, 128><<<lin128, 256, 0, stream>>>(P2, W3, b3, P1, BB);
    zero_pool_kernel<<<NB * 128 / 256, 256, 0, stream>>>(pooled);   // P2 now dead
    gathermax_pool_kernel<<<gmp128, 256, 0, stream>>>(P1, BB, idxb, pooled);

    // ---- FC on pooled ----
    fc_kernel<<<NB, 128, 0, stream>>>(pooled, Wfc, bfc, out);
}